// Round 6
// baseline (650.366 us; speedup 1.0000x reference)
//
#include <hip/hip_runtime.h>

typedef float f4 __attribute__((ext_vector_type(4)));

#define B_ 32
#define D_ 128
#define T_ 1024
#define K_ 4096
#define NROWS (B_ * T_)   // 32768
#define BM 64             // rows per workgroup; grid 512
#define LPX 132           // xs row stride (floats): %4==0 for b128 reads

// numpy computes t = a*a elementwise, THEN pairwise-sums (no fma fusion).
__device__ __forceinline__ float opaquef(float x) { asm volatile("" : "+v"(x)); return x; }

// numpy pairwise_sum base case for n=128: 8 accumulators,
// ((r0+r1)+(r2+r3))+((r4+r5)+(r6+r7)). Bit-exact replica.
__device__ float np_sumsq128(const float* a) {
  float r[8];
#pragma unroll
  for (int j = 0; j < 8; ++j) r[j] = opaquef(a[j] * a[j]);
#pragma unroll
  for (int i = 8; i < 128; i += 8) {
#pragma unroll
    for (int j = 0; j < 8; ++j) r[j] = r[j] + opaquef(a[i + j] * a[i + j]);
  }
  return ((r[0] + r[1]) + (r[2] + r[3])) + ((r[4] + r[5]) + (r[6] + r[7]));
}

__global__ void wsq_kernel(const float* __restrict__ W, float* __restrict__ wsq) {
  int k = blockIdx.x * blockDim.x + threadIdx.x;
  if (k < K_) wsq[k] = np_sumsq128(W + (size_t)k * D_);
}

// Wtb[(k>>8)][d][k&255] = W[k][d]  — K-blocked transpose, coalesced both sides.
__global__ void transpose_kernel(const float* __restrict__ W, float* __restrict__ Wtb) {
  __shared__ float t[32][33];
  int k0 = blockIdx.x * 32, d0 = blockIdx.y * 32;
  int lx = threadIdx.x & 31, ly = threadIdx.x >> 5;  // 256 thr: ly 0..7
  for (int i = ly; i < 32; i += 8) t[i][lx] = W[(size_t)(k0 + i) * D_ + d0 + lx];
  __syncthreads();
  size_t base = (size_t)(k0 >> 8) * (D_ * 256) + (k0 & 255);
  for (int i = ly; i < 32; i += 8) Wtb[base + (size_t)(d0 + i) * 256 + lx] = t[lx][i];
}

// One d2-block: 8 rows x 8 codes x 2 d's = 128 FMAs. W regs: W0/W1 = d (codes
// j0..3 / j4..7), W2/W3 = d+1. SEL picks xv elements {0,1} or {2,3}.
// Chain order per acc: strictly ascending d — bit-exact vs OpenBLAS sgemm.
#define FMA_D2(W0, W1, W2, W3, XV, SEL)              \
  do {                                               \
    _Pragma("unroll")                                \
    for (int i_ = 0; i_ < 8; ++i_) {                 \
      float xlo = XV[i_][2 * (SEL)];                 \
      float xhi = XV[i_][2 * (SEL) + 1];             \
      _Pragma("unroll")                              \
      for (int j_ = 0; j_ < 4; ++j_) {               \
        float s_ = acc[i_][j_];                      \
        s_ = __fmaf_rn(xlo, W0[j_], s_);             \
        s_ = __fmaf_rn(xhi, W2[j_], s_);             \
        acc[i_][j_] = s_;                            \
      }                                              \
      _Pragma("unroll")                              \
      for (int j_ = 0; j_ < 4; ++j_) {               \
        float s_ = acc[i_][j_ + 4];                  \
        s_ = __fmaf_rn(xlo, W1[j_], s_);             \
        s_ = __fmaf_rn(xhi, W3[j_], s_);             \
        acc[i_][j_ + 4] = s_;                        \
      }                                              \
    }                                                \
  } while (0)

#define LDW(R0, R1, R2, R3)                          \
  R0 = *(const f4*)(pwb);                            \
  R1 = *(const f4*)(pwb + 16);                       \
  R2 = *(const f4*)(pwb + 1024);                     \
  R3 = *(const f4*)(pwb + 1040);                     \
  pwb += 2048;

__global__ __launch_bounds__(256, 2) void argmin_kernel(
    const float* __restrict__ x, const float* __restrict__ Wtb,
    const float* __restrict__ wsq, int* __restrict__ qout,
    float* __restrict__ out2) {
  __shared__ float xs[BM][LPX];
  __shared__ float xsqs[BM];
  const int tid = threadIdx.x;
  const int blk = blockIdx.x;
  const int b  = blk >> 4;            // / (T_/BM)
  const int t0 = (blk & 15) * BM;
  const int tx = tid & 31;            // 8 consecutive codes per 256-tile
  const int ty = tid >> 5;            // rows ty*8 .. ty*8+7

  // stage x tile: xs[tt][d] = x[b, d, t0+tt]   (coalesced along t)
  {
    int tt = tid & 63;
    int d0 = (tid >> 6) * 32;
    for (int dd = 0; dd < 32; ++dd) {
      int d = d0 + dd;
      xs[tt][d] = x[((size_t)b * D_ + d) * T_ + t0 + tt];
    }
  }
  __syncthreads();
  if (tid < BM) xsqs[tid] = np_sumsq128(&xs[tid][0]);
  __syncthreads();

  float xq[8];
#pragma unroll
  for (int i = 0; i < 8; ++i) xq[i] = xsqs[ty * 8 + i];

  float m1[8];
  int   i1[8];
#pragma unroll
  for (int i = 0; i < 8; ++i) { m1[i] = 3.4e38f; i1[i] = 0x7fffffff; }

  for (int kt = 0; kt < K_ / 256; ++kt) {
    const char* pwb = (const char*)Wtb + (size_t)kt * (D_ * 256 * 4) + tx * 32;

    float acc[8][8];
#pragma unroll
    for (int i = 0; i < 8; ++i)
#pragma unroll
      for (int j = 0; j < 8; ++j) acc[i][j] = 0.f;

    // 4-buffer rotation, straight-line: a=d, b=d+2, c=d+4, e=d+6 (being loaded)
    f4 a0, a1, a2, a3, b0, b1, b2, b3, c0, c1, c2, c3, e0, e1, e2, e3;
    LDW(a0, a1, a2, a3)   // d0,d1
    LDW(b0, b1, b2, b3)   // d2,d3
    LDW(c0, c1, c2, c3)   // d4,d5

    for (int s = 0; s < 16; ++s) {
      const int d = s * 8;
      f4 xv[8];
#pragma unroll
      for (int i = 0; i < 8; ++i) xv[i] = *(const f4*)&xs[ty * 8 + i][d];
      LDW(e0, e1, e2, e3)                 // load d+6  (used 3 blocks later)
      FMA_D2(a0, a1, a2, a3, xv, 0);      // d, d+1
      LDW(a0, a1, a2, a3)                 // load d+8
      FMA_D2(b0, b1, b2, b3, xv, 1);      // d+2, d+3
#pragma unroll
      for (int i = 0; i < 8; ++i) xv[i] = *(const f4*)&xs[ty * 8 + i][d + 4];
      LDW(b0, b1, b2, b3)                 // load d+10
      FMA_D2(c0, c1, c2, c3, xv, 0);      // d+4, d+5
      LDW(c0, c1, c2, c3)                 // load d+12 (last iter: slack overread)
      FMA_D2(e0, e1, e2, e3, xv, 1);      // d+6, d+7
    }

    // epilogue: ascending k within thread (j ascending)
    const int kb = kt * 256 + tx * 8;
    f4 wqa = *(const f4*)&wsq[kb];
    f4 wqb = *(const f4*)&wsq[kb + 4];
#pragma unroll
    for (int j = 0; j < 4; ++j) {
#pragma unroll
      for (int i = 0; i < 8; ++i) {
        float t = __fmaf_rn(-2.0f, acc[i][j], wqa[j]);  // RN(wq - 2*mm)
        float v = __fadd_rn(t, xq[i]);                   // quantizing add
        if (v < m1[i]) { m1[i] = v; i1[i] = kb + j; }    // strict < => first occ.
      }
    }
#pragma unroll
    for (int j = 0; j < 4; ++j) {
#pragma unroll
      for (int i = 0; i < 8; ++i) {
        float t = __fmaf_rn(-2.0f, acc[i][j + 4], wqb[j]);
        float v = __fadd_rn(t, xq[i]);
        if (v < m1[i]) { m1[i] = v; i1[i] = kb + 4 + j; }
      }
    }
  }

  // cross-lane reduce over tx (masks <32 stay within the 32-lane half-wave)
#pragma unroll
  for (int i = 0; i < 8; ++i) {
    float m = m1[i];
    int   idx = i1[i];
#pragma unroll
    for (int mask = 16; mask >= 1; mask >>= 1) {
      float mo = __shfl_xor(m, mask);
      int   io = __shfl_xor(idx, mask);
      if (mo < m || (mo == m && io < idx)) { m = mo; idx = io; }
    }
    if (tx == 0) {
      int rg = b * T_ + t0 + ty * 8 + i;
      qout[rg] = idx;
      out2[rg] = (float)idx;
    }
  }
}

// out0[r, d] = W[q[r], d]  — coalesced along d
__global__ void scatter0_kernel(const float* __restrict__ W,
                                const int* __restrict__ q,
                                float* __restrict__ out0) {
  int r = blockIdx.x * 2 + (threadIdx.x >> 7);
  int d = threadIdx.x & 127;
  out0[(size_t)r * D_ + d] = W[(size_t)q[r] * D_ + d];
}

// out1[b, d, t] = W[q[b,t], d]  — coalesced along t
__global__ void scatter1_kernel(const float* __restrict__ W,
                                const int* __restrict__ q,
                                float* __restrict__ out1) {
  int b = blockIdx.x >> 7;
  int d = blockIdx.x & 127;
  for (int t = threadIdx.x; t < T_; t += 256) {
    int k = q[b * T_ + t];
    out1[((size_t)b * D_ + d) * T_ + t] = W[(size_t)k * D_ + d];
  }
}

extern "C" void kernel_launch(void* const* d_in, const int* in_sizes, int n_in,
                              void* d_out, int out_size, void* d_ws, size_t ws_size,
                              hipStream_t stream) {
  const float* x = (const float*)d_in[0];
  const float* W = (const float*)d_in[1];
  float* out  = (float*)d_out;
  float* out0 = out;                           // [B,T,D]  4194304
  float* out1 = out + (size_t)NROWS * D_;      // [B,D,T]  4194304
  float* out2 = out + 2 * (size_t)NROWS * D_;  // [B,T]    32768 (as float)

  float* wsq = (float*)d_ws;                              // 16 KB
  int*   q   = (int*)((char*)d_ws + K_ * sizeof(float));  // 128 KB
  size_t base = K_ * sizeof(float) + NROWS * sizeof(int);
  // Wtb (2 MB + 8 KB prefetch slack): workspace if it fits, else stash in out0
  // (argmin reads it, scatter0 overwrites it afterwards — stream-ordered).
  float* Wtb = (ws_size >= base + (size_t)K_ * D_ * sizeof(float) + 8192)
                   ? (float*)((char*)d_ws + base)
                   : out0;

  wsq_kernel<<<K_ / 256, 256, 0, stream>>>(W, wsq);
  {
    dim3 g(K_ / 32, D_ / 32);
    transpose_kernel<<<g, 256, 0, stream>>>(W, Wtb);
  }
  argmin_kernel<<<NROWS / BM, 256, 0, stream>>>(x, Wtb, wsq, q, out2);
  scatter0_kernel<<<NROWS / 2, 256, 0, stream>>>(W, q, out0);
  scatter1_kernel<<<B_ * D_, 256, 0, stream>>>(W, q, out1);
}

// Round 7
// 482.253 us; speedup vs baseline: 1.3486x; 1.3486x over previous
//
#include <hip/hip_runtime.h>

typedef float f4 __attribute__((ext_vector_type(4)));

#define B_ 32
#define D_ 128
#define T_ 1024
#define K_ 4096
#define NROWS (B_ * T_)   // 32768
#define BM 64             // rows per workgroup; grid 512
#define LPX 132           // xs row stride (floats): %4==0 for b128 reads

#define SCHED_FENCE() __builtin_amdgcn_sched_barrier(0)

// numpy computes t = a*a elementwise, THEN pairwise-sums (no fma fusion).
__device__ __forceinline__ float opaquef(float x) { asm volatile("" : "+v"(x)); return x; }

// numpy pairwise_sum base case for n=128: 8 accumulators,
// ((r0+r1)+(r2+r3))+((r4+r5)+(r6+r7)). Bit-exact replica.
__device__ float np_sumsq128(const float* a) {
  float r[8];
#pragma unroll
  for (int j = 0; j < 8; ++j) r[j] = opaquef(a[j] * a[j]);
#pragma unroll
  for (int i = 8; i < 128; i += 8) {
#pragma unroll
    for (int j = 0; j < 8; ++j) r[j] = r[j] + opaquef(a[i + j] * a[i + j]);
  }
  return ((r[0] + r[1]) + (r[2] + r[3])) + ((r[4] + r[5]) + (r[6] + r[7]));
}

__global__ void wsq_kernel(const float* __restrict__ W, float* __restrict__ wsq) {
  int k = blockIdx.x * blockDim.x + threadIdx.x;
  if (k < K_) wsq[k] = np_sumsq128(W + (size_t)k * D_);
}

// Wtb[(k>>8)][d][k&255] = W[k][d]  — K-blocked transpose, coalesced both sides.
__global__ void transpose_kernel(const float* __restrict__ W, float* __restrict__ Wtb) {
  __shared__ float t[32][33];
  int k0 = blockIdx.x * 32, d0 = blockIdx.y * 32;
  int lx = threadIdx.x & 31, ly = threadIdx.x >> 5;  // 256 thr: ly 0..7
  for (int i = ly; i < 32; i += 8) t[i][lx] = W[(size_t)(k0 + i) * D_ + d0 + lx];
  __syncthreads();
  size_t base = (size_t)(k0 >> 8) * (D_ * 256) + (k0 & 255);
  for (int i = ly; i < 32; i += 8) Wtb[base + (size_t)(d0 + i) * 256 + lx] = t[lx][i];
}

// One d2-block: 8 rows x 8 codes x 2 d's = 128 FMAs. W0/W1 = d (codes j0..3 /
// j4..7), W2/W3 = d+1. SEL picks x elements {0,1} or {2,3} of the f4.
// Chain order per acc: strictly ascending d — bit-exact vs OpenBLAS sgemm.
#define FMA_D2(W0, W1, W2, W3, XV, SEL)              \
  do {                                               \
    _Pragma("unroll")                                \
    for (int i_ = 0; i_ < 8; ++i_) {                 \
      float xlo = XV[i_][2 * (SEL)];                 \
      float xhi = XV[i_][2 * (SEL) + 1];             \
      _Pragma("unroll")                              \
      for (int j_ = 0; j_ < 4; ++j_) {               \
        float s_ = acc[i_][j_];                      \
        s_ = __fmaf_rn(xlo, W0[j_], s_);             \
        s_ = __fmaf_rn(xhi, W2[j_], s_);             \
        acc[i_][j_] = s_;                            \
      }                                              \
      _Pragma("unroll")                              \
      for (int j_ = 0; j_ < 4; ++j_) {               \
        float s_ = acc[i_][j_ + 4];                  \
        s_ = __fmaf_rn(xlo, W1[j_], s_);             \
        s_ = __fmaf_rn(xhi, W3[j_], s_);             \
        acc[i_][j_ + 4] = s_;                        \
      }                                              \
    }                                                \
  } while (0)

#define LDW(R0, R1, R2, R3)                          \
  R0 = *(const f4*)(pwb);                            \
  R1 = *(const f4*)(pwb + 16);                       \
  R2 = *(const f4*)(pwb + 1024);                     \
  R3 = *(const f4*)(pwb + 1040);                     \
  pwb += 2048;

__global__ __launch_bounds__(256, 2) void argmin_kernel(
    const float* __restrict__ x, const float* __restrict__ Wtb,
    const float* __restrict__ wsq, int* __restrict__ qout,
    float* __restrict__ out2) {
  __shared__ float xs[BM][LPX];
  __shared__ float xsqs[BM];
  const int tid = threadIdx.x;
  const int blk = blockIdx.x;
  const int b  = blk >> 4;            // / (T_/BM)
  const int t0 = (blk & 15) * BM;
  const int tx = tid & 31;            // 8 consecutive codes per 256-tile
  const int ty = tid >> 5;            // rows ty*8 .. ty*8+7

  // stage x tile: xs[tt][d] = x[b, d, t0+tt]   (coalesced along t)
  {
    int tt = tid & 63;
    int d0 = (tid >> 6) * 32;
    for (int dd = 0; dd < 32; ++dd) {
      int d = d0 + dd;
      xs[tt][d] = x[((size_t)b * D_ + d) * T_ + t0 + tt];
    }
  }
  __syncthreads();
  if (tid < BM) xsqs[tid] = np_sumsq128(&xs[tid][0]);
  __syncthreads();

  float xq[8];
#pragma unroll
  for (int i = 0; i < 8; ++i) xq[i] = xsqs[ty * 8 + i];

  float m1[8];
  int   i1[8];
#pragma unroll
  for (int i = 0; i < 8; ++i) { m1[i] = 3.4e38f; i1[i] = 0x7fffffff; }

  for (int kt = 0; kt < K_ / 256; ++kt) {
    const char* pwb = (const char*)Wtb + (size_t)kt * (D_ * 256 * 4) + tx * 32;

    float acc[8][8];
#pragma unroll
    for (int i = 0; i < 8; ++i)
#pragma unroll
      for (int j = 0; j < 8; ++j) acc[i][j] = 0.f;

    // 4-buffer rotation, pinned with sched_barrier fences so the LLVM
    // scheduler cannot collapse the pipeline (r5/r6 lesson: it will).
    f4 a0, a1, a2, a3, b0, b1, b2, b3, c0, c1, c2, c3, e0, e1, e2, e3;
    LDW(a0, a1, a2, a3)   // d0,d1
    LDW(b0, b1, b2, b3)   // d2,d3
    LDW(c0, c1, c2, c3)   // d4,d5

    for (int s = 0; s < 16; ++s) {
      const int d = s * 8;
      f4 xv[8];
#pragma unroll
      for (int i = 0; i < 8; ++i) xv[i] = *(const f4*)&xs[ty * 8 + i][d];
      LDW(e0, e1, e2, e3)                 // load d+6 (used 3 blocks later)
      SCHED_FENCE();
      FMA_D2(a0, a1, a2, a3, xv, 0);      // d, d+1
      SCHED_FENCE();
      LDW(a0, a1, a2, a3)                 // load d+8
      SCHED_FENCE();
      FMA_D2(b0, b1, b2, b3, xv, 1);      // d+2, d+3
      SCHED_FENCE();
      f4 xw[8];
#pragma unroll
      for (int i = 0; i < 8; ++i) xw[i] = *(const f4*)&xs[ty * 8 + i][d + 4];
      LDW(b0, b1, b2, b3)                 // load d+10
      SCHED_FENCE();
      FMA_D2(c0, c1, c2, c3, xw, 0);      // d+4, d+5
      SCHED_FENCE();
      LDW(c0, c1, c2, c3)                 // load d+12 (last iter: slack overread)
      SCHED_FENCE();
      FMA_D2(e0, e1, e2, e3, xw, 1);      // d+6, d+7
      SCHED_FENCE();
    }

    // epilogue: ascending k within thread (j ascending)
    const int kb = kt * 256 + tx * 8;
    f4 wqa = *(const f4*)&wsq[kb];
    f4 wqb = *(const f4*)&wsq[kb + 4];
#pragma unroll
    for (int j = 0; j < 4; ++j) {
#pragma unroll
      for (int i = 0; i < 8; ++i) {
        float t = __fmaf_rn(-2.0f, acc[i][j], wqa[j]);  // RN(wq - 2*mm)
        float v = __fadd_rn(t, xq[i]);                   // quantizing add
        if (v < m1[i]) { m1[i] = v; i1[i] = kb + j; }    // strict < => first occ.
      }
    }
#pragma unroll
    for (int j = 0; j < 4; ++j) {
#pragma unroll
      for (int i = 0; i < 8; ++i) {
        float t = __fmaf_rn(-2.0f, acc[i][j + 4], wqb[j]);
        float v = __fadd_rn(t, xq[i]);
        if (v < m1[i]) { m1[i] = v; i1[i] = kb + 4 + j; }
      }
    }
  }

  // cross-lane reduce over tx (masks <32 stay within the 32-lane half-wave)
#pragma unroll
  for (int i = 0; i < 8; ++i) {
    float m = m1[i];
    int   idx = i1[i];
#pragma unroll
    for (int mask = 16; mask >= 1; mask >>= 1) {
      float mo = __shfl_xor(m, mask);
      int   io = __shfl_xor(idx, mask);
      if (mo < m || (mo == m && io < idx)) { m = mo; idx = io; }
    }
    if (tx == 0) {
      int rg = b * T_ + t0 + ty * 8 + i;
      qout[rg] = idx;
      out2[rg] = (float)idx;
    }
  }
}

// out0[r, d] = W[q[r], d]  — coalesced along d
__global__ void scatter0_kernel(const float* __restrict__ W,
                                const int* __restrict__ q,
                                float* __restrict__ out0) {
  int r = blockIdx.x * 2 + (threadIdx.x >> 7);
  int d = threadIdx.x & 127;
  out0[(size_t)r * D_ + d] = W[(size_t)q[r] * D_ + d];
}

// out1[b, d, t] = W[q[b,t], d]  — coalesced along t
__global__ void scatter1_kernel(const float* __restrict__ W,
                                const int* __restrict__ q,
                                float* __restrict__ out1) {
  int b = blockIdx.x >> 7;
  int d = blockIdx.x & 127;
  for (int t = threadIdx.x; t < T_; t += 256) {
    int k = q[b * T_ + t];
    out1[((size_t)b * D_ + d) * T_ + t] = W[(size_t)k * D_ + d];
  }
}

extern "C" void kernel_launch(void* const* d_in, const int* in_sizes, int n_in,
                              void* d_out, int out_size, void* d_ws, size_t ws_size,
                              hipStream_t stream) {
  const float* x = (const float*)d_in[0];
  const float* W = (const float*)d_in[1];
  float* out  = (float*)d_out;
  float* out0 = out;                           // [B,T,D]  4194304
  float* out1 = out + (size_t)NROWS * D_;      // [B,D,T]  4194304
  float* out2 = out + 2 * (size_t)NROWS * D_;  // [B,T]    32768 (as float)

  float* wsq = (float*)d_ws;                              // 16 KB
  int*   q   = (int*)((char*)d_ws + K_ * sizeof(float));  // 128 KB
  size_t base = K_ * sizeof(float) + NROWS * sizeof(int);
  // Wtb (2 MB + 8 KB prefetch slack): workspace if it fits, else stash in out0
  // (argmin reads it, scatter0 overwrites it afterwards — stream-ordered).
  float* Wtb = (ws_size >= base + (size_t)K_ * D_ * sizeof(float) + 8192)
                   ? (float*)((char*)d_ws + base)
                   : out0;

  wsq_kernel<<<K_ / 256, 256, 0, stream>>>(W, wsq);
  {
    dim3 g(K_ / 32, D_ / 32);
    transpose_kernel<<<g, 256, 0, stream>>>(W, Wtb);
  }
  argmin_kernel<<<NROWS / BM, 256, 0, stream>>>(x, Wtb, wsq, q, out2);
  scatter0_kernel<<<NROWS / 2, 256, 0, stream>>>(W, q, out0);
  scatter1_kernel<<<B_ * D_, 256, 0, stream>>>(W, q, out1);
}